// Round 1
// baseline (118.192 us; speedup 1.0000x reference)
//
#include <hip/hip_runtime.h>

// PatchwiseHadamard collapses algebraically:
//   out = alpha * x  everywhere, where alpha = dot(out_w, conv_w)
//   plus 256*beta at each 256x256 patch's (0,0) corner,
//   where beta = dot(out_w, conv_b) + out_b.
// Proof: H_norm is orthogonal+symmetric so H(HxH^T)H^T = x; the bias term
// beta*J transforms to (row-sum_i)(row-sum_j)/256 = 256*beta at (0,0) only.

__global__ void prep_ab(const float* __restrict__ conv_w,
                        const float* __restrict__ conv_b,
                        const float* __restrict__ out_w,
                        const float* __restrict__ out_b,
                        float* __restrict__ ab) {
    if (threadIdx.x == 0 && blockIdx.x == 0) {
        float alpha = 0.f, beta = 0.f;
#pragma unroll
        for (int c = 0; c < 16; ++c) {
            alpha = fmaf(conv_w[c], out_w[c], alpha);
            beta  = fmaf(conv_b[c], out_w[c], beta);
        }
        beta += out_b[0];
        ab[0] = alpha;
        ab[1] = 256.0f * beta;
    }
}

// x layout: (B=4, 1, H=2048, W=2048) flat. For element index e:
//   w = e & 2047, h = (e >> 11) & 2047  (B stride is 2^22, so & 2047 isolates h)
// Corner iff (w & 255) == 0 && (h & 255) == 0.
__global__ __launch_bounds__(256) void scale_corner(
        const float4* __restrict__ x, float4* __restrict__ out,
        const float* __restrict__ ab, int n4) {
    int i = blockIdx.x * blockDim.x + threadIdx.x;
    if (i >= n4) return;
    float alpha = ab[0];
    float4 v = x[i];
    v.x *= alpha;
    v.y *= alpha;
    v.z *= alpha;
    v.w *= alpha;
    int base = i << 2;  // element index of v.x; patch corners are 16B-aligned
    if (((base & 255) | ((base >> 11) & 255)) == 0) {
        v.x += ab[1];
    }
    out[i] = v;
}

extern "C" void kernel_launch(void* const* d_in, const int* in_sizes, int n_in,
                              void* d_out, int out_size, void* d_ws, size_t ws_size,
                              hipStream_t stream) {
    const float* x      = (const float*)d_in[0];
    const float* conv_w = (const float*)d_in[1];
    const float* conv_b = (const float*)d_in[2];
    const float* out_w  = (const float*)d_in[3];
    const float* out_b  = (const float*)d_in[4];
    float* out = (float*)d_out;
    float* ab  = (float*)d_ws;  // [alpha, 256*beta]

    prep_ab<<<1, 64, 0, stream>>>(conv_w, conv_b, out_w, out_b, ab);

    int n4 = out_size / 4;               // 16,777,216 / 4 = 4,194,304 float4s
    int blocks = (n4 + 255) / 256;       // 16,384 blocks
    scale_corner<<<blocks, 256, 0, stream>>>(
        (const float4*)x, (float4*)out, ab, n4);
}

// Round 2
// 115.685 us; speedup vs baseline: 1.0217x; 1.0217x over previous
//
#include <hip/hip_runtime.h>

// PatchwiseHadamard collapses algebraically:
//   out = alpha * x  everywhere, where alpha = dot(out_w, conv_w)
//   plus 256*beta at each 256x256 patch's (0,0) corner,
//   where beta = dot(out_w, conv_b) + out_b.
// Proof: H_norm (Sylvester) is orthogonal AND symmetric, so
// H(HxH^T)H^T = x; the bias term beta*J transforms to 256*beta at (0,0).
//
// Single fused kernel: thread 0 of each block computes alpha/beta from the
// 33 parameter floats (L2-broadcast, ~2 MB total traffic vs 134 MB stream),
// removing the serialized prologue kernel + d_ws round-trip from the graph.

// x layout: (B=4, 1, H=2048, W=2048) flat. For float4 index i, element
// base = 4*i: w = base & 2047, h = (base >> 11) & 2047 (B stride 2^22).
// Corner iff (w & 255) == 0 && (h & 255) == 0; corners are 16B-aligned so
// only lane-element .x can be a corner.
__global__ __launch_bounds__(256) void scale_corner(
        const float4* __restrict__ x, float4* __restrict__ out,
        const float* __restrict__ conv_w, const float* __restrict__ conv_b,
        const float* __restrict__ out_w, const float* __restrict__ out_b,
        int n4) {
    __shared__ float s_ab[2];
    if (threadIdx.x == 0) {
        float alpha = 0.f, beta = 0.f;
#pragma unroll
        for (int c = 0; c < 16; ++c) {
            alpha = fmaf(conv_w[c], out_w[c], alpha);
            beta  = fmaf(conv_b[c], out_w[c], beta);
        }
        s_ab[0] = alpha;
        s_ab[1] = 256.0f * (beta + out_b[0]);
    }
    __syncthreads();

    int i = blockIdx.x * blockDim.x + threadIdx.x;
    if (i >= n4) return;
    float alpha = s_ab[0];
    float4 v = x[i];
    v.x *= alpha;
    v.y *= alpha;
    v.z *= alpha;
    v.w *= alpha;
    int base = i << 2;
    if (((base & 255) | ((base >> 11) & 255)) == 0) {
        v.x += s_ab[1];
    }
    out[i] = v;
}

extern "C" void kernel_launch(void* const* d_in, const int* in_sizes, int n_in,
                              void* d_out, int out_size, void* d_ws, size_t ws_size,
                              hipStream_t stream) {
    const float* x      = (const float*)d_in[0];
    const float* conv_w = (const float*)d_in[1];
    const float* conv_b = (const float*)d_in[2];
    const float* out_w  = (const float*)d_in[3];
    const float* out_b  = (const float*)d_in[4];
    float* out = (float*)d_out;

    int n4 = out_size / 4;               // 16,777,216 / 4 = 4,194,304 float4s
    int blocks = (n4 + 255) / 256;       // 16,384 blocks
    scale_corner<<<blocks, 256, 0, stream>>>(
        (const float4*)x, (float4*)out, conv_w, conv_b, out_w, out_b, n4);
}